// Round 1
// baseline (93.932 us; speedup 1.0000x reference)
//
#include <hip/hip_runtime.h>
#include <math.h>

#define PCOUNT 512
#define IMG_W 256
#define IMG_H 256
#define TANX 0.5f
#define TANY 0.5f
#define NEARP 0.2f
#define BLUR 0.3f
#define AMIN (1.0f/255.0f)
#define AMAX 0.99f

// Kernel 1: per-gaussian preprocess + stable depth-rank sort + scatter to SoA in d_ws.
__global__ __launch_bounds__(PCOUNT) void preprocess_kernel(
    const float* __restrict__ means, const float* __restrict__ opac,
    const float* __restrict__ scales, const float* __restrict__ rots,
    const float* __restrict__ cols, const float* __restrict__ vm,
    const float* __restrict__ pm, float* __restrict__ g)
{
    __shared__ float s_depth[PCOUNT];
    int i = threadIdx.x;

    float mx = means[3*i], my = means[3*i+1], mz = means[3*i+2];
    float o = 1.0f / (1.0f + __expf(-opac[i]));
    float sx = __expf(scales[3*i]), sy = __expf(scales[3*i+1]), sz = __expf(scales[3*i+2]);

    float qr = rots[4*i], qx = rots[4*i+1], qy = rots[4*i+2], qz = rots[4*i+3];
    float qn = fmaxf(sqrtf(qr*qr + qx*qx + qy*qy + qz*qz), 1e-12f);
    float qi = 1.0f/qn;
    qr *= qi; qx *= qi; qy *= qi; qz *= qi;

    float R00 = 1.0f-2.0f*(qy*qy+qz*qz), R01 = 2.0f*(qx*qy - qr*qz), R02 = 2.0f*(qx*qz + qr*qy);
    float R10 = 2.0f*(qx*qy + qr*qz), R11 = 1.0f-2.0f*(qx*qx+qz*qz), R12 = 2.0f*(qy*qz - qr*qx);
    float R20 = 2.0f*(qx*qz - qr*qy), R21 = 2.0f*(qy*qz + qr*qx), R22 = 1.0f-2.0f*(qx*qx+qy*qy);

    float s0 = sx*sx, s1 = sy*sy, s2 = sz*sz;
    // cov3D = (R*diag(s)) (R*diag(s))^T  -> c_ik = sum_j R_ij R_kj s_j^2
    float c00 = R00*R00*s0 + R01*R01*s1 + R02*R02*s2;
    float c01 = R00*R10*s0 + R01*R11*s1 + R02*R12*s2;
    float c02 = R00*R20*s0 + R01*R21*s1 + R02*R22*s2;
    float c11 = R10*R10*s0 + R11*R11*s1 + R12*R12*s2;
    float c12 = R10*R20*s0 + R11*R21*s1 + R12*R22*s2;
    float c22 = R20*R20*s0 + R21*R21*s1 + R22*R22*s2;

    // view transform (vm is 4x4 row-major)
    float tx = vm[0]*mx + vm[1]*my + vm[2]*mz + vm[3];
    float ty = vm[4]*mx + vm[5]*my + vm[6]*mz + vm[7];
    float tz = vm[8]*mx + vm[9]*my + vm[10]*mz + vm[11];
    bool valid = tz > NEARP;
    float tzc = valid ? tz : 1.0f;

    float limx = 1.3f*TANX, limy = 1.3f*TANY;
    float txz = fminf(fmaxf(tx/tzc, -limx), limx)*tzc;
    float tyz = fminf(fmaxf(ty/tzc, -limy), limy)*tzc;

    float fx = (float)IMG_W/(2.0f*TANX), fy = (float)IMG_H/(2.0f*TANY);
    float J00 = fx/tzc, J02 = -fx*txz/(tzc*tzc);
    float J11 = fy/tzc, J12 = -fy*tyz/(tzc*tzc);

    // T = J @ V[:3,:3]
    float T00 = J00*vm[0] + J02*vm[8];
    float T01 = J00*vm[1] + J02*vm[9];
    float T02 = J00*vm[2] + J02*vm[10];
    float T10 = J11*vm[4] + J12*vm[8];
    float T11 = J11*vm[5] + J12*vm[9];
    float T12 = J11*vm[6] + J12*vm[10];

    // M = T @ cov3D ; cov2D = M @ T^T + blur*I
    float M00 = T00*c00 + T01*c01 + T02*c02;
    float M01 = T00*c01 + T01*c11 + T02*c12;
    float M02 = T00*c02 + T01*c12 + T02*c22;
    float M10 = T10*c00 + T11*c01 + T12*c02;
    float M11 = T10*c01 + T11*c11 + T12*c12;
    float M12 = T10*c02 + T11*c12 + T12*c22;
    float v00 = M00*T00 + M01*T01 + M02*T02 + BLUR;
    float v01 = M00*T10 + M01*T11 + M02*T12;
    float v11 = M10*T10 + M11*T11 + M12*T12 + BLUR;

    float det = v00*v11 - v01*v01;
    det = (det == 0.0f) ? 1.0f : det;
    float idet = 1.0f/det;
    float conA = v11*idet, conB = -v01*idet, conC = v00*idet;

    // projection (pm is 4x4 row-major), ph = [m,1] @ pm^T
    float ph0 = pm[0]*mx + pm[1]*my + pm[2]*mz + pm[3];
    float ph1 = pm[4]*mx + pm[5]*my + pm[6]*mz + pm[7];
    float ph3 = pm[12]*mx + pm[13]*my + pm[14]*mz + pm[15];
    float pw = 1.0f/(ph3 + 1e-7f);
    float px = ((ph0*pw + 1.0f)*(float)IMG_W - 1.0f)*0.5f;
    float py = ((ph1*pw + 1.0f)*(float)IMG_H - 1.0f)*0.5f;

    float depth = valid ? tz : INFINITY;
    s_depth[i] = depth;
    __syncthreads();

    // stable rank: # of j with (d_j < d_i) or (d_j == d_i and j < i)
    int rank = 0;
    for (int j = 0; j < PCOUNT; ++j) {
        float dj = s_depth[j];
        rank += (int)((dj < depth) || (dj == depth && j < i));
    }

    g[0*PCOUNT + rank] = conA;
    g[1*PCOUNT + rank] = conB;
    g[2*PCOUNT + rank] = conC;
    g[3*PCOUNT + rank] = px;
    g[4*PCOUNT + rank] = py;
    g[5*PCOUNT + rank] = valid ? o : 0.0f;   // opa=0 => alpha=0 => same as ~valid mask
    g[6*PCOUNT + rank] = cols[3*i];
    g[7*PCOUNT + rank] = cols[3*i+1];
    g[8*PCOUNT + rank] = cols[3*i+2];
}

// Kernel 2: one 16x16 pixel tile per block; sequential front-to-back composite.
__global__ __launch_bounds__(256) void rasterize_kernel(
    const float* __restrict__ g, const float* __restrict__ bg, float* __restrict__ out)
{
    __shared__ float sh[9*PCOUNT];
    int t = threadIdx.x;
    #pragma unroll
    for (int k = 0; k < 18; ++k) sh[t + 256*k] = g[t + 256*k];
    __syncthreads();

    int tileX = blockIdx.x & 15, tileY = blockIdx.x >> 4;
    int lx = t & 15, ly = t >> 4;
    int x = (tileX << 4) + lx, y = (tileY << 4) + ly;
    float fxp = (float)x, fyp = (float)y;

    float T = 1.0f, cr = 0.0f, cg = 0.0f, cb = 0.0f;

    for (int i = 0; i < PCOUNT; ++i) {
        float A = sh[i], B = sh[PCOUNT+i], C = sh[2*PCOUNT+i];
        float dx = sh[3*PCOUNT+i] - fxp;
        float dy = sh[4*PCOUNT+i] - fyp;
        float power = -0.5f*(A*dx*dx + C*dy*dy) - B*dx*dy;
        if (power <= 0.0f) {
            float al = sh[5*PCOUNT+i]*__expf(power);
            if (al >= AMIN) {
                al = fminf(al, AMAX);
                float w = al*T;
                cr += w*sh[6*PCOUNT+i];
                cg += w*sh[7*PCOUNT+i];
                cb += w*sh[8*PCOUNT+i];
                T *= (1.0f - al);
            }
        }
    }

    int o = (y*IMG_W + x)*3;
    out[o+0] = cr + T*bg[0];
    out[o+1] = cg + T*bg[1];
    out[o+2] = cb + T*bg[2];
}

extern "C" void kernel_launch(void* const* d_in, const int* in_sizes, int n_in,
                              void* d_out, int out_size, void* d_ws, size_t ws_size,
                              hipStream_t stream) {
    const float* means  = (const float*)d_in[0];
    const float* opac   = (const float*)d_in[1];
    const float* scales = (const float*)d_in[2];
    const float* rots   = (const float*)d_in[3];
    const float* cols   = (const float*)d_in[4];
    const float* vm     = (const float*)d_in[5];
    const float* pm     = (const float*)d_in[6];
    // d_in[7] = campos (unused by reference math)
    const float* bg     = (const float*)d_in[8];

    float* g = (float*)d_ws;   // 9*512 floats of sorted SoA gaussian params

    preprocess_kernel<<<1, PCOUNT, 0, stream>>>(means, opac, scales, rots, cols, vm, pm, g);
    rasterize_kernel<<<256, 256, 0, stream>>>(g, bg, (float*)d_out);
}

// Round 2
// 30.919 us; speedup vs baseline: 3.0380x; 3.0380x over previous
//
#include <hip/hip_runtime.h>
#include <math.h>

#define PCOUNT 512
#define IMG_W 256
#define IMG_H 256
#define TANX 0.5f
#define TANY 0.5f
#define NEARP 0.2f
#define BLUR 0.3f
#define AMIN (1.0f/255.0f)
#define AMAX 0.99f

// ws layout: [0, 24576): params AoS, 12 floats per gaussian (A,B,C,px,py,opa,r,g,b,pad*3)
//            [24576, 32768): bbox float4 per gaussian (xlo, xhi, ylo, yhi)
#define PARAMS_OFF 0
#define BBOX_OFF   (PCOUNT*12)

// Kernel 1: per-gaussian preprocess + stable depth-rank sort + scatter (AoS) + bbox.
__global__ __launch_bounds__(PCOUNT) void preprocess_kernel(
    const float* __restrict__ means, const float* __restrict__ opac,
    const float* __restrict__ scales, const float* __restrict__ rots,
    const float* __restrict__ cols, const float* __restrict__ vm,
    const float* __restrict__ pm, float* __restrict__ ws)
{
    __shared__ float s_depth[PCOUNT];
    int i = threadIdx.x;

    float mx = means[3*i], my = means[3*i+1], mz = means[3*i+2];
    float o = 1.0f / (1.0f + __expf(-opac[i]));
    float sx = __expf(scales[3*i]), sy = __expf(scales[3*i+1]), sz = __expf(scales[3*i+2]);

    float qr = rots[4*i], qx = rots[4*i+1], qy = rots[4*i+2], qz = rots[4*i+3];
    float qn = fmaxf(sqrtf(qr*qr + qx*qx + qy*qy + qz*qz), 1e-12f);
    float qi = 1.0f/qn;
    qr *= qi; qx *= qi; qy *= qi; qz *= qi;

    float R00 = 1.0f-2.0f*(qy*qy+qz*qz), R01 = 2.0f*(qx*qy - qr*qz), R02 = 2.0f*(qx*qz + qr*qy);
    float R10 = 2.0f*(qx*qy + qr*qz), R11 = 1.0f-2.0f*(qx*qx+qz*qz), R12 = 2.0f*(qy*qz - qr*qx);
    float R20 = 2.0f*(qx*qz - qr*qy), R21 = 2.0f*(qy*qz + qr*qx), R22 = 1.0f-2.0f*(qx*qx+qy*qy);

    float s0 = sx*sx, s1 = sy*sy, s2 = sz*sz;
    float c00 = R00*R00*s0 + R01*R01*s1 + R02*R02*s2;
    float c01 = R00*R10*s0 + R01*R11*s1 + R02*R12*s2;
    float c02 = R00*R20*s0 + R01*R21*s1 + R02*R22*s2;
    float c11 = R10*R10*s0 + R11*R11*s1 + R12*R12*s2;
    float c12 = R10*R20*s0 + R11*R21*s1 + R12*R22*s2;
    float c22 = R20*R20*s0 + R21*R21*s1 + R22*R22*s2;

    float tx = vm[0]*mx + vm[1]*my + vm[2]*mz + vm[3];
    float ty = vm[4]*mx + vm[5]*my + vm[6]*mz + vm[7];
    float tz = vm[8]*mx + vm[9]*my + vm[10]*mz + vm[11];
    bool valid = tz > NEARP;
    float tzc = valid ? tz : 1.0f;

    float limx = 1.3f*TANX, limy = 1.3f*TANY;
    float txz = fminf(fmaxf(tx/tzc, -limx), limx)*tzc;
    float tyz = fminf(fmaxf(ty/tzc, -limy), limy)*tzc;

    float fx = (float)IMG_W/(2.0f*TANX), fy = (float)IMG_H/(2.0f*TANY);
    float J00 = fx/tzc, J02 = -fx*txz/(tzc*tzc);
    float J11 = fy/tzc, J12 = -fy*tyz/(tzc*tzc);

    float T00 = J00*vm[0] + J02*vm[8];
    float T01 = J00*vm[1] + J02*vm[9];
    float T02 = J00*vm[2] + J02*vm[10];
    float T10 = J11*vm[4] + J12*vm[8];
    float T11 = J11*vm[5] + J12*vm[9];
    float T12 = J11*vm[6] + J12*vm[10];

    float M00 = T00*c00 + T01*c01 + T02*c02;
    float M01 = T00*c01 + T01*c11 + T02*c12;
    float M02 = T00*c02 + T01*c12 + T02*c22;
    float M10 = T10*c00 + T11*c01 + T12*c02;
    float M11 = T10*c01 + T11*c11 + T12*c12;
    float M12 = T10*c02 + T11*c12 + T12*c22;
    float v00 = M00*T00 + M01*T01 + M02*T02 + BLUR;
    float v01 = M00*T10 + M01*T11 + M02*T12;
    float v11 = M10*T10 + M11*T11 + M12*T12 + BLUR;

    float det = v00*v11 - v01*v01;
    det = (det == 0.0f) ? 1.0f : det;
    float idet = 1.0f/det;
    float conA = v11*idet, conB = -v01*idet, conC = v00*idet;

    float ph0 = pm[0]*mx + pm[1]*my + pm[2]*mz + pm[3];
    float ph1 = pm[4]*mx + pm[5]*my + pm[6]*mz + pm[7];
    float ph3 = pm[12]*mx + pm[13]*my + pm[14]*mz + pm[15];
    float pw = 1.0f/(ph3 + 1e-7f);
    float px = ((ph0*pw + 1.0f)*(float)IMG_W - 1.0f)*0.5f;
    float py = ((ph1*pw + 1.0f)*(float)IMG_H - 1.0f)*0.5f;

    float opa_eff = valid ? o : 0.0f;

    // Exact contributing extent: alpha >= AMIN  <=>  d^T Con d <= 2*ln(opa*255).
    // Ellipse bbox half-extents: sqrt(r2 * cov2D_diag). +1px margin for fp safety.
    float xlo = 1e9f, xhi = -1e9f, ylo = 1e9f, yhi = -1e9f;
    float oa = opa_eff * 255.0f;
    if (oa > 1.0f) {
        float r2 = 2.0f * __logf(oa);
        float dxm = sqrtf(r2 * v00) + 1.0f;
        float dym = sqrtf(r2 * v11) + 1.0f;
        xlo = px - dxm; xhi = px + dxm;
        ylo = py - dym; yhi = py + dym;
    }

    float depth = valid ? tz : INFINITY;
    s_depth[i] = depth;
    __syncthreads();

    // stable rank via float4-vectorized scan
    int rank = 0;
    const float4* sd4 = (const float4*)s_depth;
    for (int j4 = 0; j4 < PCOUNT/4; ++j4) {
        float4 d = sd4[j4];
        int jb = j4 * 4;
        rank += (int)((d.x < depth) || (d.x == depth && (jb+0) < i));
        rank += (int)((d.y < depth) || (d.y == depth && (jb+1) < i));
        rank += (int)((d.z < depth) || (d.z == depth && (jb+2) < i));
        rank += (int)((d.w < depth) || (d.w == depth && (jb+3) < i));
    }

    float* p = ws + PARAMS_OFF + rank*12;
    p[0] = conA; p[1] = conB; p[2] = conC; p[3] = px;
    p[4] = py;   p[5] = opa_eff; p[6] = cols[3*i]; p[7] = cols[3*i+1];
    p[8] = cols[3*i+2]; p[9] = 0.0f; p[10] = 0.0f; p[11] = 0.0f;

    float4* bb = (float4*)(ws + BBOX_OFF);
    bb[rank] = make_float4(xlo, xhi, ylo, yhi);
}

// Kernel 2: per 16x16 tile: ordered ballot-compaction of bbox hits, then composite.
__global__ __launch_bounds__(256) void rasterize_kernel(
    const float* __restrict__ ws, const float* __restrict__ bg, float* __restrict__ out)
{
    __shared__ unsigned short list[PCOUNT];
    __shared__ int s_wcnt[4];
    __shared__ int s_base;

    int t = threadIdx.x;
    int wave = t >> 6, lane = t & 63;
    int tileX = blockIdx.x & 15, tileY = blockIdx.x >> 4;
    float tx0 = (float)(tileX << 4), tx1 = tx0 + 15.0f;
    float ty0 = (float)(tileY << 4), ty1 = ty0 + 15.0f;

    if (t == 0) s_base = 0;
    __syncthreads();

    const float4* bb = (const float4*)(ws + BBOX_OFF);
    #pragma unroll
    for (int c = 0; c < 2; ++c) {
        int gidx = c*256 + t;
        float4 b = bb[gidx];
        bool hit = (b.x <= tx1) & (b.y >= tx0) & (b.z <= ty1) & (b.w >= ty0);
        unsigned long long m = __ballot(hit);
        int rank = __popcll(m & ((1ull << lane) - 1ull));
        if (lane == 0) s_wcnt[wave] = __popcll(m);
        __syncthreads();
        int off = s_base;
        for (int w = 0; w < wave; ++w) off += s_wcnt[w];
        if (hit) list[off + rank] = (unsigned short)gidx;
        __syncthreads();
        if (t == 0) s_base += s_wcnt[0] + s_wcnt[1] + s_wcnt[2] + s_wcnt[3];
        __syncthreads();
    }
    int total = s_base;

    int lx = t & 15, ly = t >> 4;
    float fxp = tx0 + (float)lx, fyp = ty0 + (float)ly;

    float T = 1.0f, cr = 0.0f, cg = 0.0f, cb = 0.0f;
    const float4* params = (const float4*)(ws + PARAMS_OFF);

    for (int i = 0; i < total; ++i) {
        int idx = list[i];
        float4 p0 = params[idx*3 + 0];  // A,B,C,px
        float4 p1 = params[idx*3 + 1];  // py,opa,cr,cg
        float4 p2 = params[idx*3 + 2];  // cb,-,-,-
        float dx = p0.w - fxp;
        float dy = p1.x - fyp;
        float power = -0.5f*(p0.x*dx*dx + p0.z*dy*dy) - p0.y*dx*dy;
        if (power <= 0.0f) {
            float al = p1.y * __expf(power);
            if (al >= AMIN) {
                al = fminf(al, AMAX);
                float w = al * T;
                cr += w * p1.z;
                cg += w * p1.w;
                cb += w * p2.x;
                T *= (1.0f - al);
            }
        }
    }

    int x = (tileX << 4) + lx, y = (tileY << 4) + ly;
    int o = (y*IMG_W + x)*3;
    out[o+0] = cr + T*bg[0];
    out[o+1] = cg + T*bg[1];
    out[o+2] = cb + T*bg[2];
}

extern "C" void kernel_launch(void* const* d_in, const int* in_sizes, int n_in,
                              void* d_out, int out_size, void* d_ws, size_t ws_size,
                              hipStream_t stream) {
    const float* means  = (const float*)d_in[0];
    const float* opac   = (const float*)d_in[1];
    const float* scales = (const float*)d_in[2];
    const float* rots   = (const float*)d_in[3];
    const float* cols   = (const float*)d_in[4];
    const float* vm     = (const float*)d_in[5];
    const float* pm     = (const float*)d_in[6];
    const float* bg     = (const float*)d_in[8];

    float* ws = (float*)d_ws;

    preprocess_kernel<<<1, PCOUNT, 0, stream>>>(means, opac, scales, rots, cols, vm, pm, ws);
    rasterize_kernel<<<256, 256, 0, stream>>>(ws, bg, (float*)d_out);
}

// Round 3
// 13.235 us; speedup vs baseline: 7.0971x; 2.3361x over previous
//
#include <hip/hip_runtime.h>
#include <math.h>

#define PCOUNT 512
#define IMG_W 256
#define IMG_H 256
#define TANX 0.5f
#define TANY 0.5f
#define NEARP 0.2f
#define BLUR 0.3f
#define AMIN (1.0f/255.0f)
#define AMAX 0.99f

// One block per 16x16 tile. Each block redundantly preprocesses all 512
// gaussians (2 per thread), keeps only those whose exact contributing
// ellipse overlaps the tile, sorts the survivors by depth, composites.
__global__ __launch_bounds__(256) void fused_raster_kernel(
    const float* __restrict__ means, const float* __restrict__ opac,
    const float* __restrict__ scales, const float* __restrict__ rots,
    const float* __restrict__ cols, const float* __restrict__ vm,
    const float* __restrict__ pm, const float* __restrict__ bg,
    float* __restrict__ out)
{
    __shared__ float s_params[PCOUNT * 12];      // A,B,C,px,py,opa,r,g,b,pad3 per hit
    __shared__ float s_depth[PCOUNT];            // depth per hit (compacted order)
    __shared__ unsigned short s_order[PCOUNT];   // depth-sorted order of hits
    __shared__ int s_wcnt[4];
    __shared__ int s_base;

    int t = threadIdx.x;
    int wave = t >> 6, lane = t & 63;
    int tileX = blockIdx.x & 15, tileY = blockIdx.x >> 4;
    float tx0 = (float)(tileX << 4), tx1 = tx0 + 15.0f;
    float ty0 = (float)(tileY << 4), ty1 = ty0 + 15.0f;

    if (t == 0) s_base = 0;
    __syncthreads();

    // ---- preprocess + compact (2 chunks of 256 gaussians) ----
    #pragma unroll
    for (int c = 0; c < 2; ++c) {
        int g = c * 256 + t;

        float mx = means[3*g], my = means[3*g+1], mz = means[3*g+2];
        float o = 1.0f / (1.0f + __expf(-opac[g]));
        float sx = __expf(scales[3*g]), sy = __expf(scales[3*g+1]), sz = __expf(scales[3*g+2]);

        float qr = rots[4*g], qx = rots[4*g+1], qy = rots[4*g+2], qz = rots[4*g+3];
        float qn = fmaxf(sqrtf(qr*qr + qx*qx + qy*qy + qz*qz), 1e-12f);
        float qi = 1.0f/qn;
        qr *= qi; qx *= qi; qy *= qi; qz *= qi;

        float R00 = 1.0f-2.0f*(qy*qy+qz*qz), R01 = 2.0f*(qx*qy - qr*qz), R02 = 2.0f*(qx*qz + qr*qy);
        float R10 = 2.0f*(qx*qy + qr*qz), R11 = 1.0f-2.0f*(qx*qx+qz*qz), R12 = 2.0f*(qy*qz - qr*qx);
        float R20 = 2.0f*(qx*qz - qr*qy), R21 = 2.0f*(qy*qz + qr*qx), R22 = 1.0f-2.0f*(qx*qx+qy*qy);

        float s0 = sx*sx, s1 = sy*sy, s2 = sz*sz;
        float c00 = R00*R00*s0 + R01*R01*s1 + R02*R02*s2;
        float c01 = R00*R10*s0 + R01*R11*s1 + R02*R12*s2;
        float c02 = R00*R20*s0 + R01*R21*s1 + R02*R22*s2;
        float c11 = R10*R10*s0 + R11*R11*s1 + R12*R12*s2;
        float c12 = R10*R20*s0 + R11*R21*s1 + R12*R22*s2;
        float c22 = R20*R20*s0 + R21*R21*s1 + R22*R22*s2;

        float tx = vm[0]*mx + vm[1]*my + vm[2]*mz + vm[3];
        float ty = vm[4]*mx + vm[5]*my + vm[6]*mz + vm[7];
        float tz = vm[8]*mx + vm[9]*my + vm[10]*mz + vm[11];
        bool valid = tz > NEARP;
        float tzc = valid ? tz : 1.0f;

        float limx = 1.3f*TANX, limy = 1.3f*TANY;
        float txz = fminf(fmaxf(tx/tzc, -limx), limx)*tzc;
        float tyz = fminf(fmaxf(ty/tzc, -limy), limy)*tzc;

        float fx = (float)IMG_W/(2.0f*TANX), fy = (float)IMG_H/(2.0f*TANY);
        float J00 = fx/tzc, J02 = -fx*txz/(tzc*tzc);
        float J11 = fy/tzc, J12 = -fy*tyz/(tzc*tzc);

        float T00 = J00*vm[0] + J02*vm[8];
        float T01 = J00*vm[1] + J02*vm[9];
        float T02 = J00*vm[2] + J02*vm[10];
        float T10 = J11*vm[4] + J12*vm[8];
        float T11 = J11*vm[5] + J12*vm[9];
        float T12 = J11*vm[6] + J12*vm[10];

        float M00 = T00*c00 + T01*c01 + T02*c02;
        float M01 = T00*c01 + T01*c11 + T02*c12;
        float M02 = T00*c02 + T01*c12 + T02*c22;
        float M10 = T10*c00 + T11*c01 + T12*c02;
        float M11 = T10*c01 + T11*c11 + T12*c12;
        float M12 = T10*c02 + T11*c12 + T12*c22;
        float v00 = M00*T00 + M01*T01 + M02*T02 + BLUR;
        float v01 = M00*T10 + M01*T11 + M02*T12;
        float v11 = M10*T10 + M11*T11 + M12*T12 + BLUR;

        float det = v00*v11 - v01*v01;
        det = (det == 0.0f) ? 1.0f : det;
        float idet = 1.0f/det;
        float conA = v11*idet, conB = -v01*idet, conC = v00*idet;

        float ph0 = pm[0]*mx + pm[1]*my + pm[2]*mz + pm[3];
        float ph1 = pm[4]*mx + pm[5]*my + pm[6]*mz + pm[7];
        float ph3 = pm[12]*mx + pm[13]*my + pm[14]*mz + pm[15];
        float pw = 1.0f/(ph3 + 1e-7f);
        float px = ((ph0*pw + 1.0f)*(float)IMG_W - 1.0f)*0.5f;
        float py = ((ph1*pw + 1.0f)*(float)IMG_H - 1.0f)*0.5f;

        float opa_eff = valid ? o : 0.0f;

        // exact contributing extent: alpha >= AMIN <=> d^T Con d <= 2 ln(255*opa)
        bool hit = false;
        float oa = opa_eff * 255.0f;
        if (oa > 1.0f) {
            float r2 = 2.0f * __logf(oa);
            float dxm = sqrtf(r2 * v00) + 1.0f;
            float dym = sqrtf(r2 * v11) + 1.0f;
            hit = (px - dxm <= tx1) & (px + dxm >= tx0) &
                  (py - dym <= ty1) & (py + dym >= ty0);
        }

        unsigned long long m = __ballot(hit);
        int rnk = __popcll(m & ((1ull << lane) - 1ull));
        if (lane == 0) s_wcnt[wave] = __popcll(m);
        __syncthreads();
        int off = s_base;
        for (int w = 0; w < wave; ++w) off += s_wcnt[w];
        if (hit) {
            int slot = off + rnk;
            float* p = &s_params[slot * 12];
            p[0] = conA; p[1] = conB; p[2] = conC; p[3] = px;
            p[4] = py;   p[5] = opa_eff;
            p[6] = cols[3*g]; p[7] = cols[3*g+1]; p[8] = cols[3*g+2];
            s_depth[slot] = tz;   // valid guaranteed (opa_eff>0 => valid)
        }
        __syncthreads();
        if (t == 0) s_base += s_wcnt[0] + s_wcnt[1] + s_wcnt[2] + s_wcnt[3];
        __syncthreads();
    }
    int total = s_base;

    // ---- stable depth sort of the survivors (compacted order == index order) ----
    if (t < total) {
        float dk = s_depth[t];
        int rank = 0;
        for (int j = 0; j < total; ++j) {
            float dj = s_depth[j];
            rank += (int)((dj < dk) || (dj == dk && j < t));
        }
        s_order[rank] = (unsigned short)t;
    }
    __syncthreads();

    // ---- composite ----
    int lx = t & 15, ly = t >> 4;
    float fxp = tx0 + (float)lx, fyp = ty0 + (float)ly;

    float T = 1.0f, cr = 0.0f, cg = 0.0f, cb = 0.0f;
    for (int i = 0; i < total; ++i) {
        int k = s_order[i];
        const float* p = &s_params[k * 12];
        float4 p0 = *(const float4*)(p);      // A,B,C,px
        float4 p1 = *(const float4*)(p + 4);  // py,opa,r,g
        float pb  = p[8];
        float dx = p0.w - fxp;
        float dy = p1.x - fyp;
        float power = -0.5f*(p0.x*dx*dx + p0.z*dy*dy) - p0.y*dx*dy;
        if (power <= 0.0f) {
            float al = p1.y * __expf(power);
            if (al >= AMIN) {
                al = fminf(al, AMAX);
                float w = al * T;
                cr += w * p1.z;
                cg += w * p1.w;
                cb += w * pb;
                T *= (1.0f - al);
            }
        }
    }

    int x = (tileX << 4) + lx, y = (tileY << 4) + ly;
    int o = (y*IMG_W + x)*3;
    out[o+0] = cr + T*bg[0];
    out[o+1] = cg + T*bg[1];
    out[o+2] = cb + T*bg[2];
}

extern "C" void kernel_launch(void* const* d_in, const int* in_sizes, int n_in,
                              void* d_out, int out_size, void* d_ws, size_t ws_size,
                              hipStream_t stream) {
    const float* means  = (const float*)d_in[0];
    const float* opac   = (const float*)d_in[1];
    const float* scales = (const float*)d_in[2];
    const float* rots   = (const float*)d_in[3];
    const float* cols   = (const float*)d_in[4];
    const float* vm     = (const float*)d_in[5];
    const float* pm     = (const float*)d_in[6];
    const float* bg     = (const float*)d_in[8];

    fused_raster_kernel<<<256, 256, 0, stream>>>(
        means, opac, scales, rots, cols, vm, pm, bg, (float*)d_out);
}

// Round 4
// 10.626 us; speedup vs baseline: 8.8400x; 1.2456x over previous
//
#include <hip/hip_runtime.h>
#include <math.h>

#define PCOUNT 512
#define IMG_W 256
#define IMG_H 256
#define TANX 0.5f
#define TANY 0.5f
#define NEARP 0.2f
#define BLUR 0.3f
#define AMIN (1.0f/255.0f)
#define AMAX 0.99f

// One block per 16x16 tile, 1024 threads (16 waves).
// Threads <512 preprocess one gaussian each (redundant per block; runs on all
// 256 CUs in parallel). Ballot-compaction keeps survivors whose exact
// contributing ellipse (alpha >= 1/255) overlaps the tile, stable depth-rank
// sort, then a 4-way segmented front-to-back composite (thread = segment x
// pixel) combined via the associativity of the over operator.
__global__ __launch_bounds__(1024) void fused_raster_kernel(
    const float* __restrict__ means, const float* __restrict__ opac,
    const float* __restrict__ scales, const float* __restrict__ rots,
    const float* __restrict__ cols, const float* __restrict__ vm,
    const float* __restrict__ pm, const float* __restrict__ bg,
    float* __restrict__ out)
{
    __shared__ float s_params[PCOUNT * 12];      // A,B,C,px,py,opa,r,g,b per hit
    __shared__ float s_depth[PCOUNT];
    __shared__ unsigned short s_order[PCOUNT];
    __shared__ float4 s_part[4][256];            // per-segment (cr,cg,cb,T)
    __shared__ int s_wcnt[16];
    __shared__ int s_total;

    int t = threadIdx.x;
    int wave = t >> 6, lane = t & 63;
    int tileX = blockIdx.x & 15, tileY = blockIdx.x >> 4;
    float tx0 = (float)(tileX << 4), tx1 = tx0 + 15.0f;
    float ty0 = (float)(tileY << 4), ty1 = ty0 + 15.0f;

    // ---- preprocess (one gaussian per thread, t < 512) ----
    bool hit = false;
    float conA = 0, conB = 0, conC = 0, px = 0, py = 0, opa_eff = 0, tz = 0;
    int g = t;
    if (t < PCOUNT) {
        float mx = means[3*g], my = means[3*g+1], mz = means[3*g+2];
        float o = 1.0f / (1.0f + __expf(-opac[g]));
        float sx = __expf(scales[3*g]), sy = __expf(scales[3*g+1]), sz = __expf(scales[3*g+2]);

        float qr = rots[4*g], qx = rots[4*g+1], qy = rots[4*g+2], qz = rots[4*g+3];
        float qn = fmaxf(sqrtf(qr*qr + qx*qx + qy*qy + qz*qz), 1e-12f);
        float qi = 1.0f/qn;
        qr *= qi; qx *= qi; qy *= qi; qz *= qi;

        float R00 = 1.0f-2.0f*(qy*qy+qz*qz), R01 = 2.0f*(qx*qy - qr*qz), R02 = 2.0f*(qx*qz + qr*qy);
        float R10 = 2.0f*(qx*qy + qr*qz), R11 = 1.0f-2.0f*(qx*qx+qz*qz), R12 = 2.0f*(qy*qz - qr*qx);
        float R20 = 2.0f*(qx*qz - qr*qy), R21 = 2.0f*(qy*qz + qr*qx), R22 = 1.0f-2.0f*(qx*qx+qy*qy);

        float s0 = sx*sx, s1 = sy*sy, s2 = sz*sz;
        float c00 = R00*R00*s0 + R01*R01*s1 + R02*R02*s2;
        float c01 = R00*R10*s0 + R01*R11*s1 + R02*R12*s2;
        float c02 = R00*R20*s0 + R01*R21*s1 + R02*R22*s2;
        float c11 = R10*R10*s0 + R11*R11*s1 + R12*R12*s2;
        float c12 = R10*R20*s0 + R11*R21*s1 + R12*R22*s2;
        float c22 = R20*R20*s0 + R21*R21*s1 + R22*R22*s2;

        float tvx = vm[0]*mx + vm[1]*my + vm[2]*mz + vm[3];
        float tvy = vm[4]*mx + vm[5]*my + vm[6]*mz + vm[7];
        tz = vm[8]*mx + vm[9]*my + vm[10]*mz + vm[11];
        bool valid = tz > NEARP;
        float tzc = valid ? tz : 1.0f;

        float limx = 1.3f*TANX, limy = 1.3f*TANY;
        float txz = fminf(fmaxf(tvx/tzc, -limx), limx)*tzc;
        float tyz = fminf(fmaxf(tvy/tzc, -limy), limy)*tzc;

        float fx = (float)IMG_W/(2.0f*TANX), fy = (float)IMG_H/(2.0f*TANY);
        float J00 = fx/tzc, J02 = -fx*txz/(tzc*tzc);
        float J11 = fy/tzc, J12 = -fy*tyz/(tzc*tzc);

        float T00 = J00*vm[0] + J02*vm[8];
        float T01 = J00*vm[1] + J02*vm[9];
        float T02 = J00*vm[2] + J02*vm[10];
        float T10 = J11*vm[4] + J12*vm[8];
        float T11 = J11*vm[5] + J12*vm[9];
        float T12 = J11*vm[6] + J12*vm[10];

        float M00 = T00*c00 + T01*c01 + T02*c02;
        float M01 = T00*c01 + T01*c11 + T02*c12;
        float M02 = T00*c02 + T01*c12 + T02*c22;
        float M10 = T10*c00 + T11*c01 + T12*c02;
        float M11 = T10*c01 + T11*c11 + T12*c12;
        float M12 = T10*c02 + T11*c12 + T12*c22;
        float v00 = M00*T00 + M01*T01 + M02*T02 + BLUR;
        float v01 = M00*T10 + M01*T11 + M02*T12;
        float v11 = M10*T10 + M11*T11 + M12*T12 + BLUR;

        float det = v00*v11 - v01*v01;
        det = (det == 0.0f) ? 1.0f : det;
        float idet = 1.0f/det;
        conA = v11*idet; conB = -v01*idet; conC = v00*idet;

        float ph0 = pm[0]*mx + pm[1]*my + pm[2]*mz + pm[3];
        float ph1 = pm[4]*mx + pm[5]*my + pm[6]*mz + pm[7];
        float ph3 = pm[12]*mx + pm[13]*my + pm[14]*mz + pm[15];
        float pw = 1.0f/(ph3 + 1e-7f);
        px = ((ph0*pw + 1.0f)*(float)IMG_W - 1.0f)*0.5f;
        py = ((ph1*pw + 1.0f)*(float)IMG_H - 1.0f)*0.5f;

        opa_eff = valid ? o : 0.0f;

        float oa = opa_eff * 255.0f;
        if (oa > 1.0f) {
            float r2 = 2.0f * __logf(oa);
            float dxm = sqrtf(r2 * v00) + 1.0f;
            float dym = sqrtf(r2 * v11) + 1.0f;
            hit = (px - dxm <= tx1) & (px + dxm >= tx0) &
                  (py - dym <= ty1) & (py + dym >= ty0);
        }
    }

    // ---- ordered ballot compaction (single pass, 16 waves) ----
    unsigned long long m = __ballot(hit);
    int rnk = __popcll(m & ((1ull << lane) - 1ull));
    if (lane == 0) s_wcnt[wave] = __popcll(m);
    __syncthreads();
    int off = 0;
    for (int w = 0; w < wave; ++w) off += s_wcnt[w];
    if (hit) {
        int slot = off + rnk;
        float* p = &s_params[slot * 12];
        p[0] = conA; p[1] = conB; p[2] = conC; p[3] = px;
        p[4] = py;   p[5] = opa_eff;
        p[6] = cols[3*g]; p[7] = cols[3*g+1]; p[8] = cols[3*g+2];
        s_depth[slot] = tz;
    }
    if (t == 0) {
        int s = 0;
        #pragma unroll
        for (int w = 0; w < 16; ++w) s += s_wcnt[w];
        s_total = s;
    }
    __syncthreads();
    int total = s_total;

    // ---- stable depth-rank sort of survivors ----
    if (t < total) {
        float dk = s_depth[t];
        int rank = 0;
        for (int j = 0; j < total; ++j) {
            float dj = s_depth[j];
            rank += (int)((dj < dk) || (dj == dk && j < t));
        }
        s_order[rank] = (unsigned short)t;
    }
    __syncthreads();

    // ---- 4-way segmented composite ----
    int p = t & 255, seg = t >> 8;
    int lx = p & 15, ly = p >> 4;
    float fxp = tx0 + (float)lx, fyp = ty0 + (float)ly;

    int seglen = (total + 3) >> 2;
    int i0 = seg * seglen;
    int i1 = min(i0 + seglen, total);

    float T = 1.0f, cr = 0.0f, cg = 0.0f, cb = 0.0f;
    for (int i = i0; i < i1; ++i) {
        int k = s_order[i];
        const float* pp = &s_params[k * 12];
        float4 p0 = *(const float4*)(pp);      // A,B,C,px
        float4 p1 = *(const float4*)(pp + 4);  // py,opa,r,g
        float pb  = pp[8];
        float dx = p0.w - fxp;
        float dy = p1.x - fyp;
        float power = -0.5f*(p0.x*dx*dx + p0.z*dy*dy) - p0.y*dx*dy;
        if (power <= 0.0f) {
            float al = p1.y * __expf(power);
            if (al >= AMIN) {
                al = fminf(al, AMAX);
                float w = al * T;
                cr += w * p1.z;
                cg += w * p1.w;
                cb += w * pb;
                T *= (1.0f - al);
            }
        }
    }
    s_part[seg][p] = make_float4(cr, cg, cb, T);
    __syncthreads();

    // ---- combine segments + store ----
    if (t < 256) {
        float4 r0 = s_part[0][t], r1 = s_part[1][t], r2 = s_part[2][t], r3 = s_part[3][t];
        float Tt  = r0.w * r1.w * r2.w * r3.w;
        float ocr = r0.x + r0.w*(r1.x + r1.w*(r2.x + r2.w*r3.x));
        float ocg = r0.y + r0.w*(r1.y + r1.w*(r2.y + r2.w*r3.y));
        float ocb = r0.z + r0.w*(r1.z + r1.w*(r2.z + r2.w*r3.z));

        int x = (tileX << 4) + (t & 15), y = (tileY << 4) + (t >> 4);
        int o = (y*IMG_W + x)*3;
        out[o+0] = ocr + Tt*bg[0];
        out[o+1] = ocg + Tt*bg[1];
        out[o+2] = ocb + Tt*bg[2];
    }
}

extern "C" void kernel_launch(void* const* d_in, const int* in_sizes, int n_in,
                              void* d_out, int out_size, void* d_ws, size_t ws_size,
                              hipStream_t stream) {
    const float* means  = (const float*)d_in[0];
    const float* opac   = (const float*)d_in[1];
    const float* scales = (const float*)d_in[2];
    const float* rots   = (const float*)d_in[3];
    const float* cols   = (const float*)d_in[4];
    const float* vm     = (const float*)d_in[5];
    const float* pm     = (const float*)d_in[6];
    const float* bg     = (const float*)d_in[8];

    fused_raster_kernel<<<256, 1024, 0, stream>>>(
        means, opac, scales, rots, cols, vm, pm, bg, (float*)d_out);
}